// Round 1
// baseline (531.964 us; speedup 1.0000x reference)
//
#include <hip/hip_runtime.h>

#define B_   2
#define S_   2048
#define D_   1024
#define H_   16
#define DK_  64
#define DFF_ 4096
#define NTOK (B_ * S_)   // 4096

typedef __bf16 bf16x8 __attribute__((ext_vector_type(8)));
typedef __bf16 bf16x4 __attribute__((ext_vector_type(4)));
typedef float  f32x4  __attribute__((ext_vector_type(4)));

// ---------------------------------------------------------------------------
// async global->LDS 16B copy. LDS dest is wave-uniform base + lane*16.
// ---------------------------------------------------------------------------
__device__ __forceinline__ void ld16(const __bf16* g, __bf16* l) {
  __builtin_amdgcn_global_load_lds(
      (const __attribute__((address_space(1))) void*)g,
      (__attribute__((address_space(3))) void*)l, 16, 0, 0);
}

// ---------------------------------------------------------------------------
// m97-style GEMM core: C[128x128] tile of A[M,K] @ W[N,K]^T (both bf16,
// K contiguous). 256 threads = 4 waves, each wave 64x64 = 4x4 MFMA tiles.
// ---------------------------------------------------------------------------
__device__ __forceinline__ void gemm_core_128(
    const __bf16* __restrict__ A, const __bf16* __restrict__ W, int K,
    int rowA0, int rowW0, f32x4 (&acc)[4][4], __bf16* As, __bf16* Bs)
{
  const int t   = threadIdx.x;
  const int lane = t & 63;
  const int wv  = t >> 6;
  const int wm  = (wv >> 1) << 6;
  const int wn  = (wv & 1) << 6;
  const int l15 = lane & 15;
  const int q4  = lane >> 4;

#pragma unroll
  for (int i = 0; i < 4; ++i)
#pragma unroll
    for (int j = 0; j < 4; ++j)
      acc[i][j] = (f32x4){0.f, 0.f, 0.f, 0.f};

  // staging map: thread t, pass p covers tile element offset 8*(t + 256p)
  // == row-major [128][32]: row = (t+256p)/4, k8 = t&3.
  const __bf16* gA = A + (size_t)(rowA0 + (t >> 2)) * K + (t & 3) * 8;
  const __bf16* gW = W + (size_t)(rowW0 + (t >> 2)) * K + (t & 3) * 8;
  __bf16* lA = As + wv * 512;   // wave-uniform LDS base (elements)
  __bf16* lB = Bs + wv * 512;
  const size_t g2 = (size_t)64 * K;

  for (int k0 = 0; k0 < K; k0 += 32) {
    ld16(gA + k0,      lA);
    ld16(gA + k0 + g2, lA + 2048);
    ld16(gW + k0,      lB);
    ld16(gW + k0 + g2, lB + 2048);
    __syncthreads();
    bf16x8 af[4], bw[4];
#pragma unroll
    for (int i = 0; i < 4; ++i)
      af[i] = *(const bf16x8*)(As + ((wm + 16 * i + l15) << 5) + q4 * 8);
#pragma unroll
    for (int j = 0; j < 4; ++j)
      bw[j] = *(const bf16x8*)(Bs + ((wn + 16 * j + l15) << 5) + q4 * 8);
#pragma unroll
    for (int i = 0; i < 4; ++i)
#pragma unroll
      for (int j = 0; j < 4; ++j)
        acc[i][j] = __builtin_amdgcn_mfma_f32_16x16x32_bf16(af[i], bw[j], acc[i][j], 0, 0, 0);
    __syncthreads();
  }
}

// ---------------------------------------------------------------------------
// QKV: one launch, grid.z selects {Q,K,V}. V stored transposed vt[b,h,d,s].
// ---------------------------------------------------------------------------
__global__ __launch_bounds__(256) void gemm_qkv(
    const __bf16* __restrict__ xn,
    const __bf16* __restrict__ wqb, const __bf16* __restrict__ wkb,
    const __bf16* __restrict__ wvb,
    __bf16* __restrict__ qo, __bf16* __restrict__ ko, __bf16* __restrict__ vto)
{
  __shared__ __align__(16) __bf16 As[128 * 32];
  __shared__ __align__(16) __bf16 Bs[128 * 32];
  const __bf16* W = blockIdx.z == 0 ? wqb : (blockIdx.z == 1 ? wkb : wvb);
  f32x4 acc[4][4];
  gemm_core_128(xn, W, D_, blockIdx.y * 128, blockIdx.x * 128, acc, As, Bs);

  const int t = threadIdx.x, lane = t & 63, wv = t >> 6;
  const int wm = (wv >> 1) << 6, wn = (wv & 1) << 6;
  const int l15 = lane & 15, q4 = lane >> 4;
  const int row0 = blockIdx.y * 128 + wm;
  const int col0 = blockIdx.x * 128 + wn;

  if (blockIdx.z < 2) {
    __bf16* o = blockIdx.z == 0 ? qo : ko;
#pragma unroll
    for (int i = 0; i < 4; ++i)
#pragma unroll
      for (int j = 0; j < 4; ++j)
#pragma unroll
        for (int r = 0; r < 4; ++r) {
          int row = row0 + 16 * i + q4 * 4 + r;
          int col = col0 + 16 * j + l15;
          o[(size_t)row * D_ + col] = (__bf16)acc[i][j][r];
        }
  } else {
#pragma unroll
    for (int i = 0; i < 4; ++i)
#pragma unroll
      for (int j = 0; j < 4; ++j)
#pragma unroll
        for (int r = 0; r < 4; ++r) {
          int tok = row0 + 16 * i + q4 * 4 + r;
          int c   = col0 + 16 * j + l15;
          int b = tok >> 11, s = tok & (S_ - 1);
          int h = c >> 6,  d = c & (DK_ - 1);
          vto[(size_t)((b * H_ + h) * DK_ + d) * S_ + s] = (__bf16)acc[i][j][r];
        }
  }
}

// ---------------------------------------------------------------------------
// general GEMM: mode 1 = bias+relu -> bf16; 3 = resid add -> f32;
//               4 = resid+bias -> f32
// ---------------------------------------------------------------------------
__global__ __launch_bounds__(256) void gemm_gen(
    const __bf16* __restrict__ A, const __bf16* __restrict__ W, int K, int NC,
    int mode, __bf16* __restrict__ outb, float* __restrict__ outf,
    const float* __restrict__ resid, const float* __restrict__ bias)
{
  __shared__ __align__(16) __bf16 As[128 * 32];
  __shared__ __align__(16) __bf16 Bs[128 * 32];
  f32x4 acc[4][4];
  gemm_core_128(A, W, K, blockIdx.y * 128, blockIdx.x * 128, acc, As, Bs);

  const int t = threadIdx.x, lane = t & 63, wv = t >> 6;
  const int wm = (wv >> 1) << 6, wn = (wv & 1) << 6;
  const int l15 = lane & 15, q4 = lane >> 4;
  const int row0 = blockIdx.y * 128 + wm;
  const int col0 = blockIdx.x * 128 + wn;

#pragma unroll
  for (int i = 0; i < 4; ++i)
#pragma unroll
    for (int j = 0; j < 4; ++j)
#pragma unroll
      for (int r = 0; r < 4; ++r) {
        int row = row0 + 16 * i + q4 * 4 + r;
        int col = col0 + 16 * j + l15;
        float v = acc[i][j][r];
        if (mode == 1) {
          v += bias[col];
          v = fmaxf(v, 0.0f);
          outb[(size_t)row * NC + col] = (__bf16)v;
        } else if (mode == 3) {
          outf[(size_t)row * NC + col] = resid[(size_t)row * NC + col] + v;
        } else {
          outf[(size_t)row * NC + col] = resid[(size_t)row * NC + col] + v + bias[col];
        }
      }
}

// ---------------------------------------------------------------------------
// LayerNorm: alpha*(x-mean)/(std_ddof1 + eps) + bias, bf16 out. 1 block/row.
// ---------------------------------------------------------------------------
__global__ __launch_bounds__(256) void ln_kernel(
    const float* __restrict__ x, const float* __restrict__ alpha,
    const float* __restrict__ bias, __bf16* __restrict__ out)
{
  const int row = blockIdx.x;
  const int t = threadIdx.x;
  const float4 v = ((const float4*)(x + (size_t)row * D_))[t];
  float s  = v.x + v.y + v.z + v.w;
  float ss = v.x * v.x + v.y * v.y + v.z * v.z + v.w * v.w;
#pragma unroll
  for (int m = 1; m < 64; m <<= 1) {
    s  += __shfl_xor(s, m);
    ss += __shfl_xor(ss, m);
  }
  __shared__ float red[8];
  if ((t & 63) == 0) { red[t >> 6] = s; red[4 + (t >> 6)] = ss; }
  __syncthreads();
  s  = red[0] + red[1] + red[2] + red[3];
  ss = red[4] + red[5] + red[6] + red[7];
  const float mean = s * (1.0f / D_);
  float var = (ss - (float)D_ * mean * mean) * (1.0f / (D_ - 1));
  var = fmaxf(var, 0.0f);
  const float inv = 1.0f / (sqrtf(var) + 1e-6f);
  const float4 al = ((const float4*)alpha)[t];
  const float4 bi = ((const float4*)bias)[t];
  bf16x4 o;
  o.x = (__bf16)(al.x * (v.x - mean) * inv + bi.x);
  o.y = (__bf16)(al.y * (v.y - mean) * inv + bi.y);
  o.z = (__bf16)(al.z * (v.z - mean) * inv + bi.z);
  o.w = (__bf16)(al.w * (v.w - mean) * inv + bi.w);
  ((bf16x4*)(out + (size_t)row * D_))[t] = o;
}

// ---------------------------------------------------------------------------
// weight f32->bf16 casts, 6 jobs in one launch (grid.y = job)
// ---------------------------------------------------------------------------
struct CastJobs {
  const float* src[6];
  __bf16* dst[6];
  int n4[6];
};

__global__ __launch_bounds__(256) void cast_kernel(CastJobs cj) {
  const int j = blockIdx.y;
  const int i = blockIdx.x * 256 + threadIdx.x;
  if (i < cj.n4[j]) {
    float4 v = ((const float4*)cj.src[j])[i];
    bf16x4 o;
    o.x = (__bf16)v.x; o.y = (__bf16)v.y; o.z = (__bf16)v.z; o.w = (__bf16)v.w;
    ((bf16x4*)cj.dst[j])[i] = o;
  }
}

// ---------------------------------------------------------------------------
// flash attention: block = (b*H+h, qtile). BQ=128, BKV=64, DK=64.
// q,k: [NTOK][D] bf16 (head slice). vt: [B*H][DK][S] bf16. out av: [NTOK][D].
// ---------------------------------------------------------------------------
__global__ __launch_bounds__(256) void attn_kernel(
    const __bf16* __restrict__ qg, const __bf16* __restrict__ kg,
    const __bf16* __restrict__ vtg, const int* __restrict__ mask,
    __bf16* __restrict__ av)
{
  __shared__ __align__(16) __bf16 Qs[128 * DK_];   // 16 KB
  __shared__ __align__(16) __bf16 Ks[64 * DK_];    //  8 KB
  __shared__ __align__(16) __bf16 Vt[DK_ * 64];    //  8 KB
  __shared__ __align__(16) __bf16 Ps[128 * 64];    // 16 KB
  __shared__ float Mb[64];

  const int t = threadIdx.x, lane = t & 63, wv = t >> 6;
  const int l15 = lane & 15, q4 = lane >> 4;
  const int bh = blockIdx.x;
  const int b = bh >> 4, h = bh & (H_ - 1);
  const int q0 = blockIdx.y * 128;

  // stage Q tile [128][64]: 4 passes, linear-in-t mapping
  {
    const __bf16* g = qg + (size_t)(b * S_ + q0 + (t >> 3)) * D_ + h * DK_ + (t & 7) * 8;
    __bf16* lbase = Qs + wv * 512;
#pragma unroll
    for (int p = 0; p < 4; ++p)
      ld16(g + (size_t)(32 * p) * D_, lbase + 2048 * p);
  }

  float mst[2][4], lst[2][4];
  f32x4 oacc[2][4];
#pragma unroll
  for (int i = 0; i < 2; ++i)
#pragma unroll
    for (int r = 0; r < 4; ++r) { mst[i][r] = -1e30f; lst[i][r] = 0.0f; }
#pragma unroll
  for (int i = 0; i < 2; ++i)
#pragma unroll
    for (int jd = 0; jd < 4; ++jd) oacc[i][jd] = (f32x4){0.f, 0.f, 0.f, 0.f};

  for (int kv0 = 0; kv0 < S_; kv0 += 64) {
    // stage K [64][64] and V^T [64][64]
    const __bf16* gk = kg  + (size_t)(b * S_ + kv0 + (t >> 3)) * D_ + h * DK_ + (t & 7) * 8;
    const __bf16* gv = vtg + (size_t)(bh * DK_ + (t >> 3)) * S_ + kv0 + (t & 7) * 8;
    __bf16* lk = Ks + wv * 512;
    __bf16* lv = Vt + wv * 512;
    ld16(gk, lk);
    ld16(gk + (size_t)32 * D_, lk + 2048);
    ld16(gv, lv);
    ld16(gv + (size_t)32 * S_, lv + 2048);
    if (t < 64) Mb[t] = (mask[b * S_ + kv0 + t] == 0) ? -1e9f : 0.0f;
    __syncthreads();

    // scores: S = Q K^T, per-wave 32 q-rows x 64 kv
    f32x4 sacc[2][4];
#pragma unroll
    for (int i = 0; i < 2; ++i)
#pragma unroll
      for (int j = 0; j < 4; ++j) sacc[i][j] = (f32x4){0.f, 0.f, 0.f, 0.f};
#pragma unroll
    for (int s = 0; s < 2; ++s) {
      bf16x8 aq[2], bk[4];
#pragma unroll
      for (int i = 0; i < 2; ++i)
        aq[i] = *(const bf16x8*)(Qs + (wv * 32 + 16 * i + l15) * DK_ + s * 32 + q4 * 8);
#pragma unroll
      for (int j = 0; j < 4; ++j)
        bk[j] = *(const bf16x8*)(Ks + (16 * j + l15) * DK_ + s * 32 + q4 * 8);
#pragma unroll
      for (int i = 0; i < 2; ++i)
#pragma unroll
        for (int j = 0; j < 4; ++j)
          sacc[i][j] = __builtin_amdgcn_mfma_f32_16x16x32_bf16(aq[i], bk[j], sacc[i][j], 0, 0, 0);
    }

    // online softmax; write P to LDS (C-layout -> A-layout transform)
    float mb[4];
#pragma unroll
    for (int j = 0; j < 4; ++j) mb[j] = Mb[16 * j + l15];
#pragma unroll
    for (int i = 0; i < 2; ++i) {
#pragma unroll
      for (int r = 0; r < 4; ++r) {
        float pv[4];
        float vmax = -1e30f;
#pragma unroll
        for (int j = 0; j < 4; ++j) {
          pv[j] = sacc[i][j][r] * 0.125f + mb[j];
          vmax = fmaxf(vmax, pv[j]);
        }
#pragma unroll
        for (int m = 1; m < 16; m <<= 1) vmax = fmaxf(vmax, __shfl_xor(vmax, m));
        const float mnew = fmaxf(mst[i][r], vmax);
        const float al = __expf(mst[i][r] - mnew);
        mst[i][r] = mnew;
        float rsum = 0.0f;
#pragma unroll
        for (int j = 0; j < 4; ++j) {
          float p = __expf(pv[j] - mnew);
          rsum += p;
          Ps[(wv * 32 + 16 * i + q4 * 4 + r) * 64 + 16 * j + l15] = (__bf16)p;
        }
#pragma unroll
        for (int m = 1; m < 16; m <<= 1) rsum += __shfl_xor(rsum, m);
        lst[i][r] = lst[i][r] * al + rsum;
#pragma unroll
        for (int jd = 0; jd < 4; ++jd) oacc[i][jd][r] *= al;
      }
    }

    // O += P @ V  (P from LDS in A-layout; V^T rows give B-frag contiguity)
#pragma unroll
    for (int s = 0; s < 2; ++s) {
      bf16x8 ap[2], bv[4];
#pragma unroll
      for (int i = 0; i < 2; ++i)
        ap[i] = *(const bf16x8*)(Ps + (wv * 32 + 16 * i + l15) * 64 + s * 32 + q4 * 8);
#pragma unroll
      for (int jd = 0; jd < 4; ++jd)
        bv[jd] = *(const bf16x8*)(Vt + (16 * jd + l15) * 64 + s * 32 + q4 * 8);
#pragma unroll
      for (int i = 0; i < 2; ++i)
#pragma unroll
        for (int jd = 0; jd < 4; ++jd)
          oacc[i][jd] = __builtin_amdgcn_mfma_f32_16x16x32_bf16(ap[i], bv[jd], oacc[i][jd], 0, 0, 0);
    }
    __syncthreads();
  }

  // write av[token][h*64+d] = O / l
#pragma unroll
  for (int i = 0; i < 2; ++i)
#pragma unroll
    for (int jd = 0; jd < 4; ++jd)
#pragma unroll
      for (int r = 0; r < 4; ++r) {
        int tok = b * S_ + q0 + wv * 32 + 16 * i + q4 * 4 + r;
        int c   = h * DK_ + 16 * jd + l15;
        av[(size_t)tok * D_ + c] = (__bf16)(oacc[i][jd][r] / lst[i][r]);
      }
}

// ---------------------------------------------------------------------------
extern "C" void kernel_launch(void* const* d_in, const int* in_sizes, int n_in,
                              void* d_out, int out_size, void* d_ws, size_t ws_size,
                              hipStream_t stream) {
  const float* x      = (const float*)d_in[0];
  const int*   mask   = (const int*)d_in[1];
  const float* wq     = (const float*)d_in[2];
  const float* wk     = (const float*)d_in[3];
  const float* wv     = (const float*)d_in[4];
  const float* wo     = (const float*)d_in[5];
  const float* w1     = (const float*)d_in[6];
  const float* b1     = (const float*)d_in[7];
  const float* w2     = (const float*)d_in[8];
  const float* b2     = (const float*)d_in[9];
  const float* alpha1 = (const float*)d_in[10];
  const float* bias1  = (const float*)d_in[11];
  const float* alpha2 = (const float*)d_in[12];
  const float* bias2  = (const float*)d_in[13];

  char* ws = (char*)d_ws;
  __bf16* wqb = (__bf16*)(ws + ((size_t)0 << 20));
  __bf16* wkb = (__bf16*)(ws + ((size_t)2 << 20));
  __bf16* wvb = (__bf16*)(ws + ((size_t)4 << 20));
  __bf16* wob = (__bf16*)(ws + ((size_t)6 << 20));
  __bf16* w1b = (__bf16*)(ws + ((size_t)8 << 20));
  __bf16* w2b = (__bf16*)(ws + ((size_t)16 << 20));
  __bf16* xn1 = (__bf16*)(ws + ((size_t)24 << 20));  // dead after QKV
  __bf16* qb  = (__bf16*)(ws + ((size_t)32 << 20));  // dead after attention
  __bf16* kb  = (__bf16*)(ws + ((size_t)40 << 20));  // dead after attention
  __bf16* vtb = (__bf16*)(ws + ((size_t)48 << 20));  // dead after attention
  __bf16* avb = (__bf16*)(ws + ((size_t)56 << 20));  // dead after O-proj
  float*  x1  = (float*) (ws + ((size_t)64 << 20));  // live till end
  __bf16* xn2 = (__bf16*)(ws + ((size_t)56 << 20));  // reuses avb region
  __bf16* hb  = (__bf16*)(ws + ((size_t)24 << 20));  // reuses xn1/q/k/vt (32MB)
  // peak ws usage: 80 MB

  CastJobs cj;
  cj.src[0] = wq; cj.dst[0] = wqb; cj.n4[0] = D_ * D_ / 4;
  cj.src[1] = wk; cj.dst[1] = wkb; cj.n4[1] = D_ * D_ / 4;
  cj.src[2] = wv; cj.dst[2] = wvb; cj.n4[2] = D_ * D_ / 4;
  cj.src[3] = wo; cj.dst[3] = wob; cj.n4[3] = D_ * D_ / 4;
  cj.src[4] = w1; cj.dst[4] = w1b; cj.n4[4] = DFF_ * D_ / 4;
  cj.src[5] = w2; cj.dst[5] = w2b; cj.n4[5] = DFF_ * D_ / 4;
  cast_kernel<<<dim3(DFF_ * D_ / 4 / 256, 6), 256, 0, stream>>>(cj);

  // LN1: x -> xn1 (bf16)
  ln_kernel<<<dim3(NTOK), 256, 0, stream>>>(x, alpha1, bias1, xn1);

  // QKV (V transposed to vt[b,h,d,s])
  gemm_qkv<<<dim3(D_ / 128, NTOK / 128, 3), 256, 0, stream>>>(
      xn1, wqb, wkb, wvb, qb, kb, vtb);

  // flash attention -> av
  attn_kernel<<<dim3(B_ * H_, S_ / 128), 256, 0, stream>>>(qb, kb, vtb, mask, avb);

  // O-proj + residual: x1 = x + av @ wo^T  (f32)
  gemm_gen<<<dim3(D_ / 128, NTOK / 128), 256, 0, stream>>>(
      avb, wob, D_, D_, 3, nullptr, x1, x, nullptr);

  // LN2: x1 -> xn2 (bf16)
  ln_kernel<<<dim3(NTOK), 256, 0, stream>>>(x1, alpha2, bias2, xn2);

  // FFN1: h = relu(xn2 @ w1^T + b1)  (bf16)
  gemm_gen<<<dim3(DFF_ / 128, NTOK / 128), 256, 0, stream>>>(
      xn2, w1b, D_, DFF_, 1, hb, nullptr, nullptr, b1);

  // FFN2: out = x1 + h @ w2^T + b2  (f32)
  gemm_gen<<<dim3(D_ / 128, NTOK / 128), 256, 0, stream>>>(
      hb, w2b, DFF_, D_, 4, nullptr, (float*)d_out, x1, b2);
}